// Round 3
// baseline (1076.069 us; speedup 1.0000x reference)
//
#include <hip/hip_runtime.h>
#include <hip/hip_bf16.h>
#include <math.h>

#define F 128
#define H 256
#define C 40
#define CP 48          // padded class dim for MFMA stage 2
#define KHOPS 10
#define TM 32

typedef short bf16x8 __attribute__((ext_vector_type(8)));
typedef float f32x4 __attribute__((ext_vector_type(4)));

// exact 3-way bf16 split: v = f1 + f2 + f3 + O(2^-26 v); subtractions exact
__device__ __forceinline__ void split3(float v, ushort& s1, ushort& s2, ushort& s3) {
    unsigned u = __float_as_uint(v);
    float f1 = __uint_as_float(u & 0xFFFF0000u);
    s1 = (ushort)(u >> 16);
    float r = v - f1;
    unsigned ur = __float_as_uint(r);
    float f2 = __uint_as_float(ur & 0xFFFF0000u);
    s2 = (ushort)(ur >> 16);
    float r2 = r - f2;
    s3 = (ushort)(__float_as_uint(r2) >> 16);
}

// ---------------- CSR build ----------------
__global__ void k_count(const int* __restrict__ dst, int E, int* __restrict__ cnt) {
    int e = blockIdx.x * 256 + threadIdx.x;
    if (e < E) atomicAdd(&cnt[dst[e]], 1);
}

__global__ void k_scan1(const int* __restrict__ cnt, int n, int* __restrict__ bsum) {
    __shared__ int sh[256];
    int t = threadIdx.x;
    int base = blockIdx.x * 4096 + t * 16;
    int s = 0;
    for (int i = 0; i < 16; i++) { int idx = base + i; if (idx < n) s += cnt[idx]; }
    sh[t] = s; __syncthreads();
    for (int o = 128; o > 0; o >>= 1) {
        if (t < o) sh[t] += sh[t + o];
        __syncthreads();
    }
    if (t == 0) bsum[blockIdx.x] = sh[0];
}

__global__ void k_scan2(int* __restrict__ bsum, int nb) {
    if (threadIdx.x == 0) {
        int acc = 0;
        for (int i = 0; i < nb; i++) { int v = bsum[i]; bsum[i] = acc; acc += v; }
    }
}

__global__ void k_scan3(const int* __restrict__ cnt, int n, const int* __restrict__ bsum,
                        int* __restrict__ rp) {
    __shared__ int sh[256];
    int t = threadIdx.x;
    int base = blockIdx.x * 4096 + t * 16;
    int local[16]; int s = 0;
    for (int i = 0; i < 16; i++) {
        int idx = base + i;
        int v = (idx < n) ? cnt[idx] : 0;
        local[i] = v; s += v;
    }
    sh[t] = s; __syncthreads();
    for (int o = 1; o < 256; o <<= 1) {
        int v = (t >= o) ? sh[t - o] : 0;
        __syncthreads();
        sh[t] += v;
        __syncthreads();
    }
    int excl = (t == 0) ? 0 : sh[t - 1];
    int run = bsum[blockIdx.x] + excl;
    for (int i = 0; i < 16; i++) {
        int idx = base + i;
        if (idx < n) { rp[idx] = run; run += local[i]; }
    }
}

__global__ void k_fill(const int* __restrict__ src, const int* __restrict__ dst,
                       const float* __restrict__ nrm, int E, const int* __restrict__ rp,
                       int* __restrict__ cur, int2* __restrict__ ep) {
    int e = blockIdx.x * 256 + threadIdx.x;
    if (e < E) {
        int d = dst[e];
        int p = rp[d] + atomicAdd(&cur[d], 1);
        ep[p] = make_int2(src[e], __float_as_int(nrm[e]));
    }
}

// ---- W1 split to 3 bf16 arrays in B-fragment layout [h][f] (W1^T) ----
__global__ void k_wsplit(const float* __restrict__ W1, ushort* __restrict__ w1a,
                         ushort* __restrict__ w1b, ushort* __restrict__ w1c) {
    int t = blockIdx.x * 256 + threadIdx.x;
    if (t < F * H) {
        int h = t / F, f = t % F;
        ushort a, b, c;
        split3(W1[(size_t)f * H + h], a, b, c);
        w1a[t] = a; w1b[t] = b; w1c[t] = c;
    }
}

// ---- W2 split to 3 bf16 arrays in B-fragment layout [c][h], c padded to 48 ----
__global__ void k_w2split(const float* __restrict__ W2, ushort* __restrict__ w2a,
                          ushort* __restrict__ w2b, ushort* __restrict__ w2c) {
    int t = blockIdx.x * 256 + threadIdx.x;
    if (t < CP * H) {
        int c = t / H, k = t % H;
        float v = (c < C) ? W2[(size_t)k * C + c] : 0.f;
        ushort a, b, cc;
        split3(v, a, b, cc);
        w2a[t] = a; w2b[t] = b; w2c[t] = cc;
    }
}

// ------- fused MLP: MFMA split-bf16 Linear(128->256) + BN+ReLU + MFMA split-bf16
//         Linear(256->40) + snapshot-0 retain-combine -------
// LDS: xsA/B/C 3*8704 + h1s 33280 + asc/dsc 2048 + sigv 128 ~= 61.6 KB -> 2 blocks/CU
// (round-1 A/B showed 2 vs 3 blocks/CU is perf-neutral for this kernel).
// x is pre-split into bf16 triplets during staging -> stage-1 A-frags are pure
// ds_read_b128 (no serial split3 on the MFMA critical path); all 12 W-fragment
// loads per K-step batched into registers (one L2 latency exposure per K-step).
__launch_bounds__(256, 2)
__global__ void k_mlp(const float* __restrict__ x,
                      const ushort* __restrict__ w1a, const ushort* __restrict__ w1b,
                      const ushort* __restrict__ w1c,
                      const ushort* __restrict__ w2a, const ushort* __restrict__ w2b,
                      const ushort* __restrict__ w2c,
                      const float* __restrict__ b1, const float* __restrict__ g,
                      const float* __restrict__ be, const float* __restrict__ mu,
                      const float* __restrict__ var,
                      const float* __restrict__ b2, const float* __restrict__ pw,
                      const float* __restrict__ pb,
                      float* __restrict__ hbuf, float* __restrict__ oacc, int N) {
    __shared__ ushort xsA[TM][136];   // pre-split x hi   (stride 136: 16B-aligned rows)
    __shared__ ushort xsB[TM][136];   // pre-split x mid
    __shared__ ushort xsC[TM][136];   // pre-split x lo
    __shared__ float h1s[TM][260];    // fp32 h1; overlaid later: stage-2 partials + hrow
    __shared__ float ascS[H], dscS[H];
    __shared__ float sigv[TM];

    int t = threadIdx.x;
    int n0 = blockIdx.x * TM;

    // stage x tile with on-the-fly 3-way split (16 split3/thread, parallel, overlapped
    // with the global-load latency)
    for (int kk = 0; kk < 4; kk++) {
        int idx = kk * 256 + t;             // 1024 float4 = 32 nodes x 32 f4
        int node = idx >> 5, f4 = idx & 31;
        int n = n0 + node;
        float4 v = (n < N) ? ((const float4*)x)[(size_t)n * (F / 4) + f4]
                           : make_float4(0.f, 0.f, 0.f, 0.f);
        ushort4 pa, pm, pc;
        split3(v.x, pa.x, pm.x, pc.x);
        split3(v.y, pa.y, pm.y, pc.y);
        split3(v.z, pa.z, pm.z, pc.z);
        split3(v.w, pa.w, pm.w, pc.w);
        *((ushort4*)&xsA[node][f4 * 4]) = pa;
        *((ushort4*)&xsB[node][f4 * 4]) = pm;
        *((ushort4*)&xsC[node][f4 * 4]) = pc;
    }
    // BN coefficients (t == h, exactly 256 threads)
    {
        float a = g[t] * rsqrtf(var[t] + 1e-5f);
        ascS[t] = a;
        dscS[t] = (b1[t] - mu[t]) * a + be[t];
    }
    __syncthreads();

    // ---- stage 1: x @ W1 via MFMA, 6-term split product ----
    int lane = t & 63, wv = t >> 6, quad = lane >> 4, lq = lane & 15;
    int n0w = wv * 64;                      // this wave's H-chunk
    f32x4 acc[2][4];
    #pragma unroll
    for (int mi = 0; mi < 2; mi++)
        #pragma unroll
        for (int ni = 0; ni < 4; ni++)
            acc[mi][ni] = (f32x4){0.f, 0.f, 0.f, 0.f};

    #pragma unroll
    for (int ks = 0; ks < 4; ks++) {
        int k0 = ks * 32 + quad * 8;
        bf16x8 a1[2], a2[2], a3[2];
        #pragma unroll
        for (int mi = 0; mi < 2; mi++) {
            int row = mi * 16 + lq;         // A: m = lane&15
            a1[mi] = *((const bf16x8*)&xsA[row][k0]);
            a2[mi] = *((const bf16x8*)&xsB[row][k0]);
            a3[mi] = *((const bf16x8*)&xsC[row][k0]);
        }
        // batch all 12 B-fragment loads for this K-step (one latency exposure)
        bf16x8 q1[4], q2[4], q3[4];
        #pragma unroll
        for (int ni = 0; ni < 4; ni++) {
            size_t wo = (size_t)(n0w + ni * 16 + lq) * F + k0;   // B: n = lane&15
            q1[ni] = *((const bf16x8*)(w1a + wo));
            q2[ni] = *((const bf16x8*)(w1b + wo));
            q3[ni] = *((const bf16x8*)(w1c + wo));
        }
        #pragma unroll
        for (int ni = 0; ni < 4; ni++) {
            #pragma unroll
            for (int mi = 0; mi < 2; mi++) {
                acc[mi][ni] = __builtin_amdgcn_mfma_f32_16x16x32_bf16(a1[mi], q1[ni], acc[mi][ni], 0, 0, 0);
                acc[mi][ni] = __builtin_amdgcn_mfma_f32_16x16x32_bf16(a1[mi], q2[ni], acc[mi][ni], 0, 0, 0);
                acc[mi][ni] = __builtin_amdgcn_mfma_f32_16x16x32_bf16(a2[mi], q1[ni], acc[mi][ni], 0, 0, 0);
                acc[mi][ni] = __builtin_amdgcn_mfma_f32_16x16x32_bf16(a1[mi], q3[ni], acc[mi][ni], 0, 0, 0);
                acc[mi][ni] = __builtin_amdgcn_mfma_f32_16x16x32_bf16(a2[mi], q2[ni], acc[mi][ni], 0, 0, 0);
                acc[mi][ni] = __builtin_amdgcn_mfma_f32_16x16x32_bf16(a3[mi], q1[ni], acc[mi][ni], 0, 0, 0);
            }
        }
    }

    // BN + ReLU, D layout col=lane&15 row=quad*4+r -> h1s
    #pragma unroll
    for (int ni = 0; ni < 4; ni++) {
        int h = n0w + ni * 16 + lq;
        float a = ascS[h], d = dscS[h];
        #pragma unroll
        for (int mi = 0; mi < 2; mi++) {
            #pragma unroll
            for (int r = 0; r < 4; r++) {
                int node = mi * 16 + quad * 4 + r;
                float v = acc[mi][ni][r] * a + d;
                h1s[node][h] = v > 0.f ? v : 0.f;
            }
        }
    }
    __syncthreads();   // h1s ready

    // ---- stage 2: h1 @ W2 via MFMA, 6-term split, K=256 split across 4 waves ----
    f32x4 acc2[2][3];
    #pragma unroll
    for (int mi = 0; mi < 2; mi++)
        #pragma unroll
        for (int ni = 0; ni < 3; ni++)
            acc2[mi][ni] = (f32x4){0.f, 0.f, 0.f, 0.f};

    int kb0 = wv * 64;                      // this wave's K-chunk
    #pragma unroll
    for (int ks2 = 0; ks2 < 2; ks2++) {
        int k0 = kb0 + ks2 * 32 + quad * 8;
        bf16x8 a1[2], a2[2], a3[2];
        #pragma unroll
        for (int mi = 0; mi < 2; mi++) {
            int row = mi * 16 + lq;         // A: m = node = lane&15
            float4 f0 = *((const float4*)&h1s[row][k0]);
            float4 f1 = *((const float4*)&h1s[row][k0 + 4]);
            float fv[8] = {f0.x, f0.y, f0.z, f0.w, f1.x, f1.y, f1.z, f1.w};
            #pragma unroll
            for (int e = 0; e < 8; e++) {
                ushort sa, sb, sc;
                split3(fv[e], sa, sb, sc);
                a1[mi][e] = (short)sa; a2[mi][e] = (short)sb; a3[mi][e] = (short)sc;
            }
        }
        bf16x8 q1[3], q2[3], q3[3];
        #pragma unroll
        for (int ni = 0; ni < 3; ni++) {
            size_t wo = (size_t)(ni * 16 + lq) * H + k0;   // B: n = c = lane&15
            q1[ni] = *((const bf16x8*)(w2a + wo));
            q2[ni] = *((const bf16x8*)(w2b + wo));
            q3[ni] = *((const bf16x8*)(w2c + wo));
        }
        #pragma unroll
        for (int ni = 0; ni < 3; ni++) {
            #pragma unroll
            for (int mi = 0; mi < 2; mi++) {
                acc2[mi][ni] = __builtin_amdgcn_mfma_f32_16x16x32_bf16(a1[mi], q1[ni], acc2[mi][ni], 0, 0, 0);
                acc2[mi][ni] = __builtin_amdgcn_mfma_f32_16x16x32_bf16(a1[mi], q2[ni], acc2[mi][ni], 0, 0, 0);
                acc2[mi][ni] = __builtin_amdgcn_mfma_f32_16x16x32_bf16(a2[mi], q1[ni], acc2[mi][ni], 0, 0, 0);
                acc2[mi][ni] = __builtin_amdgcn_mfma_f32_16x16x32_bf16(a1[mi], q3[ni], acc2[mi][ni], 0, 0, 0);
                acc2[mi][ni] = __builtin_amdgcn_mfma_f32_16x16x32_bf16(a2[mi], q2[ni], acc2[mi][ni], 0, 0, 0);
                acc2[mi][ni] = __builtin_amdgcn_mfma_f32_16x16x32_bf16(a3[mi], q1[ni], acc2[mi][ni], 0, 0, 0);
            }
        }
    }
    __syncthreads();   // all h1s reads done -> h1s region reusable

    // write per-wave partials into h1s overlay: pbB[wv][node][c], stride CP=48
    float* pbB = &h1s[0][0];                // 4*32*48 = 6144 floats (<= 8320)
    #pragma unroll
    for (int mi = 0; mi < 2; mi++)
        #pragma unroll
        for (int ni = 0; ni < 3; ni++)
            #pragma unroll
            for (int r = 0; r < 4; r++) {
                int node = mi * 16 + quad * 4 + r;
                int c = ni * 16 + lq;
                pbB[wv * (TM * CP) + node * CP + c] = acc2[mi][ni][r];
            }
    __syncthreads();

    // reduce 4 wave partials + bias; stash h row; proj partial -> sigmoid
    float* hrow = &h1s[0][0] + 4 * TM * CP; // 32*40 = 1280 floats (6144..7424 <= 8320)
    {
        int ng = t >> 3, cg = t & 7;        // 32 nodes x 8 class-groups
        float p = 0.f;
        #pragma unroll
        for (int j = 0; j < 5; j++) {
            int c = cg * 5 + j;
            float h = pbB[0 * (TM * CP) + ng * CP + c]
                    + pbB[1 * (TM * CP) + ng * CP + c]
                    + pbB[2 * (TM * CP) + ng * CP + c]
                    + pbB[3 * (TM * CP) + ng * CP + c] + b2[c];
            hrow[ng * C + c] = h;
            p += h * pw[c];
        }
        #pragma unroll
        for (int m = 1; m < 8; m <<= 1) p += __shfl_xor(p, m);
        if (cg == 0) sigv[ng] = 1.f / (1.f + expf(-(p + pb[0])));
    }
    __syncthreads();

    // epilogue: write h row + out init (32 rows x 5 packs of 8 floats)
    if (t < 160) {
        int row = t / 5, p = t % 5;
        int n = n0 + row;
        if (n < N) {
            float4 a = *((const float4*)&hrow[row * C + 8 * p]);
            float4 b = *((const float4*)&hrow[row * C + 8 * p + 4]);
            float4* hp = (float4*)(hbuf + (size_t)n * C + 8 * p);
            hp[0] = a; hp[1] = b;
            float sg = sigv[row];
            float4 oa, ob;
            oa.x = sg * a.x; oa.y = sg * a.y; oa.z = sg * a.z; oa.w = sg * a.w;
            ob.x = sg * b.x; ob.y = sg * b.y; ob.z = sg * b.z; ob.w = sg * b.w;
            float4* op = (float4*)(oacc + (size_t)n * C + 8 * p);
            op[0] = oa; op[1] = ob;
        }
    }
}

// ---------------- one propagation hop, fused with retain-combine ----------------
// 320 threads: 64 nodes/block, 5 lanes/node, 2 float4 per lane.
// Masked 8-edge blocks: up to 16 row-gathers + 8 ep loads in flight per wave,
// no remainder chains (tail slots clamp index to e-1 and mask weight to 0).
// oacc read + pw loads hoisted above the edge loop (latency hidden under gathers).
// last==1: skip dead nxt write, fuse log_softmax on the final out row.
__global__ void k_hop(const float4* __restrict__ cur4, float4* __restrict__ nxt4,
                      float4* __restrict__ oacc4, const int* __restrict__ rp,
                      const int2* __restrict__ ep,
                      const float* __restrict__ pw, const float* __restrict__ pb,
                      int N, int last) {
    __shared__ float red[320];
    __shared__ float sig[64];
    __shared__ float statm[64];
    __shared__ float stats[64];
    int t = threadIdx.x;
    int nl = t / 5, p = t % 5;
    int n = blockIdx.x * 64 + nl;
    int c0 = 2 * p;
    bool ok = n < N;
    size_t o = (size_t)(ok ? n : 0) * 10 + c0;
    float4 pw0 = ((const float4*)pw)[c0];
    float4 pw1 = ((const float4*)pw)[c0 + 1];
    float4 v0 = make_float4(0.f, 0.f, 0.f, 0.f);
    float4 v1 = make_float4(0.f, 0.f, 0.f, 0.f);
    if (ok) { v0 = oacc4[o]; v1 = oacc4[o + 1]; }
    float4 a0 = make_float4(0.f, 0.f, 0.f, 0.f);
    float4 a1 = make_float4(0.f, 0.f, 0.f, 0.f);
    if (ok) {
        int b = rp[n], e = rp[n + 1];
        for (int j = b; j < e; j += 8) {
            int cnt = e - j;
            int2 ee[8];
            #pragma unroll
            for (int i = 0; i < 8; i++) {
                int jj = (i < cnt) ? (j + i) : (e - 1);   // always in-bounds
                ee[i] = ep[jj];
            }
            float4 va[8], vb[8];
            #pragma unroll
            for (int i = 0; i < 8; i++) {
                const float4* r = cur4 + (size_t)ee[i].x * 10 + c0;
                va[i] = r[0]; vb[i] = r[1];
            }
            #pragma unroll
            for (int i = 0; i < 8; i++) {
                float w = (i < cnt) ? __int_as_float(ee[i].y) : 0.f;
                a0.x += w * va[i].x; a0.y += w * va[i].y;
                a0.z += w * va[i].z; a0.w += w * va[i].w;
                a1.x += w * vb[i].x; a1.y += w * vb[i].y;
                a1.z += w * vb[i].z; a1.w += w * vb[i].w;
            }
        }
        if (!last) {
            nxt4[o] = a0;
            nxt4[o + 1] = a1;
        }
    }
    // retain-combine
    red[t] = a0.x * pw0.x + a0.y * pw0.y + a0.z * pw0.z + a0.w * pw0.w
           + a1.x * pw1.x + a1.y * pw1.y + a1.z * pw1.z + a1.w * pw1.w;
    __syncthreads();
    if (p == 0) {
        float s = red[t] + red[t + 1] + red[t + 2] + red[t + 3] + red[t + 4];
        sig[nl] = 1.f / (1.f + expf(-(s + pb[0])));
    }
    __syncthreads();
    if (ok) {
        float sg = sig[nl];
        v0.x += sg * a0.x; v0.y += sg * a0.y; v0.z += sg * a0.z; v0.w += sg * a0.w;
        v1.x += sg * a1.x; v1.y += sg * a1.y; v1.z += sg * a1.z; v1.w += sg * a1.w;
        if (!last) {
            oacc4[o] = v0;
            oacc4[o + 1] = v1;
        }
    }
    if (last) {
        // fused log_softmax over the 40 classes (spread across 5 lanes per node)
        float mx = fmaxf(fmaxf(fmaxf(v0.x, v0.y), fmaxf(v0.z, v0.w)),
                         fmaxf(fmaxf(v1.x, v1.y), fmaxf(v1.z, v1.w)));
        red[t] = ok ? mx : -1e30f;
        __syncthreads();
        if (p == 0) {
            float m = fmaxf(fmaxf(fmaxf(red[t], red[t + 1]), fmaxf(red[t + 2], red[t + 3])),
                            red[t + 4]);
            statm[nl] = m;
        }
        __syncthreads();
        float m = statm[nl];
        float s = 0.f;
        if (ok) {
            s = expf(v0.x - m) + expf(v0.y - m) + expf(v0.z - m) + expf(v0.w - m)
              + expf(v1.x - m) + expf(v1.y - m) + expf(v1.z - m) + expf(v1.w - m);
        }
        red[t] = s;
        __syncthreads();
        if (p == 0) {
            float ssum = red[t] + red[t + 1] + red[t + 2] + red[t + 3] + red[t + 4];
            stats[nl] = logf(ssum);
        }
        __syncthreads();
        if (ok) {
            float ls = statm[nl] + stats[nl];
            oacc4[o]     = make_float4(v0.x - ls, v0.y - ls, v0.z - ls, v0.w - ls);
            oacc4[o + 1] = make_float4(v1.x - ls, v1.y - ls, v1.z - ls, v1.w - ls);
        }
    }
}

extern "C" void kernel_launch(void* const* d_in, const int* in_sizes, int n_in,
                              void* d_out, int out_size, void* d_ws, size_t ws_size,
                              hipStream_t stream) {
    const float* x   = (const float*)d_in[0];
    const int*   ei  = (const int*)d_in[1];     // [2,E]: src row then dst row
    const float* nrm = (const float*)d_in[2];
    const float* W1  = (const float*)d_in[3];
    const float* b1  = (const float*)d_in[4];
    const float* g   = (const float*)d_in[5];
    const float* be  = (const float*)d_in[6];
    const float* mu  = (const float*)d_in[7];
    const float* var = (const float*)d_in[8];
    const float* W2  = (const float*)d_in[9];
    const float* b2  = (const float*)d_in[10];
    const float* pw  = (const float*)d_in[11];
    const float* pb  = (const float*)d_in[12];
    float* out = (float*)d_out;

    int N = in_sizes[0] / F;
    int E = in_sizes[2];

    char* w = (char*)d_ws;
    auto alloc = [&](size_t bytes) {
        void* p = (void*)w;
        w += ((bytes + 255) / 256) * 256;
        return p;
    };
    int*    rp     = (int*)alloc((size_t)(N + 1) * 4);
    int*    cursor = (int*)alloc((size_t)(N + 1) * 4);
    int*    bsum   = (int*)alloc(1024);
    int2*   ep     = (int2*)alloc((size_t)E * 8);
    ushort* w1a    = (ushort*)alloc((size_t)F * H * 2);
    ushort* w1b    = (ushort*)alloc((size_t)F * H * 2);
    ushort* w1c    = (ushort*)alloc((size_t)F * H * 2);
    ushort* w2a    = (ushort*)alloc((size_t)CP * H * 2);
    ushort* w2b    = (ushort*)alloc((size_t)CP * H * 2);
    ushort* w2c    = (ushort*)alloc((size_t)CP * H * 2);
    float*  bufA   = (float*)alloc((size_t)N * C * 4);
    float*  bufB   = (float*)alloc((size_t)N * C * 4);

    hipMemsetAsync(cursor, 0, (size_t)(N + 1) * 4, stream);

    k_count<<<(E + 255) / 256, 256, 0, stream>>>(ei + E, E, cursor);

    int n1 = N + 1;
    int NB = (n1 + 4095) / 4096;
    k_scan1<<<NB, 256, 0, stream>>>(cursor, n1, bsum);
    k_scan2<<<1, 64, 0, stream>>>(bsum, NB);
    k_scan3<<<NB, 256, 0, stream>>>(cursor, n1, bsum, rp);

    hipMemsetAsync(cursor, 0, (size_t)(N + 1) * 4, stream);
    k_fill<<<(E + 255) / 256, 256, 0, stream>>>(ei, ei + E, nrm, E, rp, cursor, ep);

    k_wsplit<<<(F * H + 255) / 256, 256, 0, stream>>>(W1, w1a, w1b, w1c);
    k_w2split<<<(CP * H + 255) / 256, 256, 0, stream>>>(W2, w2a, w2b, w2c);

    k_mlp<<<(N + TM - 1) / TM, 256, 0, stream>>>(x, w1a, w1b, w1c, w2a, w2b, w2c,
                                                 b1, g, be, mu, var,
                                                 b2, pw, pb, bufA, out, N);

    int nodeBlocks64 = (N + 63) / 64;
    float* cur = bufA;
    float* nxt = bufB;
    for (int k = 0; k < KHOPS; k++) {
        k_hop<<<nodeBlocks64, 320, 0, stream>>>((const float4*)cur, (float4*)nxt, (float4*)out,
                                                rp, ep, pw, pb, N, (k == KHOPS - 1) ? 1 : 0);
        float* tmp = cur; cur = nxt; nxt = tmp;
    }
}

// Round 5
// 1017.618 us; speedup vs baseline: 1.0574x; 1.0574x over previous
//
#include <hip/hip_runtime.h>
#include <hip/hip_bf16.h>
#include <math.h>

#define F 128
#define H 256
#define C 40
#define CP 48          // padded class dim for MFMA stage 2
#define RS 12          // padded row stride for hop buffers, in float4 (48 floats = 192B)
#define KHOPS 10
#define TM 32

typedef short bf16x8 __attribute__((ext_vector_type(8)));
typedef float f32x4 __attribute__((ext_vector_type(4)));

// exact 3-way bf16 split: v = f1 + f2 + f3 + O(2^-26 v); subtractions exact
__device__ __forceinline__ void split3(float v, ushort& s1, ushort& s2, ushort& s3) {
    unsigned u = __float_as_uint(v);
    float f1 = __uint_as_float(u & 0xFFFF0000u);
    s1 = (ushort)(u >> 16);
    float r = v - f1;
    unsigned ur = __float_as_uint(r);
    float f2 = __uint_as_float(ur & 0xFFFF0000u);
    s2 = (ushort)(ur >> 16);
    float r2 = r - f2;
    s3 = (ushort)(__float_as_uint(r2) >> 16);
}

// ---------------- CSR build ----------------
__global__ void k_count(const int* __restrict__ dst, int E, int* __restrict__ cnt) {
    int e = blockIdx.x * 256 + threadIdx.x;
    if (e < E) atomicAdd(&cnt[dst[e]], 1);
}

__global__ void k_scan1(const int* __restrict__ cnt, int n, int* __restrict__ bsum) {
    __shared__ int sh[256];
    int t = threadIdx.x;
    int base = blockIdx.x * 4096 + t * 16;
    int s = 0;
    for (int i = 0; i < 16; i++) { int idx = base + i; if (idx < n) s += cnt[idx]; }
    sh[t] = s; __syncthreads();
    for (int o = 128; o > 0; o >>= 1) {
        if (t < o) sh[t] += sh[t + o];
        __syncthreads();
    }
    if (t == 0) bsum[blockIdx.x] = sh[0];
}

__global__ void k_scan2(int* __restrict__ bsum, int nb) {
    if (threadIdx.x == 0) {
        int acc = 0;
        for (int i = 0; i < nb; i++) { int v = bsum[i]; bsum[i] = acc; acc += v; }
    }
}

__global__ void k_scan3(const int* __restrict__ cnt, int n, const int* __restrict__ bsum,
                        int* __restrict__ rp) {
    __shared__ int sh[256];
    int t = threadIdx.x;
    int base = blockIdx.x * 4096 + t * 16;
    int local[16]; int s = 0;
    for (int i = 0; i < 16; i++) {
        int idx = base + i;
        int v = (idx < n) ? cnt[idx] : 0;
        local[i] = v; s += v;
    }
    sh[t] = s; __syncthreads();
    for (int o = 1; o < 256; o <<= 1) {
        int v = (t >= o) ? sh[t - o] : 0;
        __syncthreads();
        sh[t] += v;
        __syncthreads();
    }
    int excl = (t == 0) ? 0 : sh[t - 1];
    int run = bsum[blockIdx.x] + excl;
    for (int i = 0; i < 16; i++) {
        int idx = base + i;
        if (idx < n) { rp[idx] = run; run += local[i]; }
    }
}

__global__ void k_fill(const int* __restrict__ src, const int* __restrict__ dst,
                       const float* __restrict__ nrm, int E, const int* __restrict__ rp,
                       int* __restrict__ cur, int2* __restrict__ ep) {
    int e = blockIdx.x * 256 + threadIdx.x;
    if (e < E) {
        int d = dst[e];
        int p = rp[d] + atomicAdd(&cur[d], 1);
        ep[p] = make_int2(src[e], __float_as_int(nrm[e]));
    }
}

// ---- W1 split to 3 bf16 arrays in B-fragment layout [h][f] (W1^T) ----
__global__ void k_wsplit(const float* __restrict__ W1, ushort* __restrict__ w1a,
                         ushort* __restrict__ w1b, ushort* __restrict__ w1c) {
    int t = blockIdx.x * 256 + threadIdx.x;
    if (t < F * H) {
        int h = t / F, f = t % F;
        ushort a, b, c;
        split3(W1[(size_t)f * H + h], a, b, c);
        w1a[t] = a; w1b[t] = b; w1c[t] = c;
    }
}

// ---- W2 split to 3 bf16 arrays in B-fragment layout [c][h], c padded to 48 ----
__global__ void k_w2split(const float* __restrict__ W2, ushort* __restrict__ w2a,
                          ushort* __restrict__ w2b, ushort* __restrict__ w2c) {
    int t = blockIdx.x * 256 + threadIdx.x;
    if (t < CP * H) {
        int c = t / H, k = t % H;
        float v = (c < C) ? W2[(size_t)k * C + c] : 0.f;
        ushort a, b, cc;
        split3(v, a, b, cc);
        w2a[t] = a; w2b[t] = b; w2c[t] = cc;
    }
}

// ------- fused MLP (round-2 proven form): MFMA split-bf16 Linear(128->256) + BN+ReLU
//         + MFMA split-bf16 Linear(256->40) + snapshot-0 retain-combine -------
// LDS: xs 16896 + h1s 33280 + asc/dsc 2048 + sigv 128 ~= 52.4 KB -> 3 blocks/CU.
__launch_bounds__(256, 3)
__global__ void k_mlp(const float* __restrict__ x,
                      const ushort* __restrict__ w1a, const ushort* __restrict__ w1b,
                      const ushort* __restrict__ w1c,
                      const ushort* __restrict__ w2a, const ushort* __restrict__ w2b,
                      const ushort* __restrict__ w2c,
                      const float* __restrict__ b1, const float* __restrict__ g,
                      const float* __restrict__ be, const float* __restrict__ mu,
                      const float* __restrict__ var,
                      const float* __restrict__ b2, const float* __restrict__ pw,
                      const float* __restrict__ pb,
                      float* __restrict__ hbuf, float* __restrict__ oacc, int N) {
    __shared__ float xs[TM][132];     // fp32 x tile (stage 1 A operand)
    __shared__ float h1s[TM][260];    // fp32 h1; also overlaid: stage-2 partials + hrow
    __shared__ float ascS[H], dscS[H];
    __shared__ float sigv[TM];

    int t = threadIdx.x;
    int n0 = blockIdx.x * TM;

    // stage x tile (fp32)
    for (int kk = 0; kk < 4; kk++) {
        int idx = kk * 256 + t;             // 1024 float4 = 32 nodes x 32 f4
        int node = idx >> 5, f4 = idx & 31;
        int n = n0 + node;
        float4 v = (n < N) ? ((const float4*)x)[(size_t)n * (F / 4) + f4]
                           : make_float4(0.f, 0.f, 0.f, 0.f);
        *((float4*)&xs[node][f4 * 4]) = v;
    }
    // BN coefficients (t == h, exactly 256 threads)
    {
        float a = g[t] * rsqrtf(var[t] + 1e-5f);
        ascS[t] = a;
        dscS[t] = (b1[t] - mu[t]) * a + be[t];
    }
    __syncthreads();

    // ---- stage 1: x @ W1 via MFMA, 6-term split product; split3 done in-register ----
    int lane = t & 63, wv = t >> 6, quad = lane >> 4, lq = lane & 15;
    int n0w = wv * 64;                      // this wave's H-chunk
    f32x4 acc[2][4];
    #pragma unroll
    for (int mi = 0; mi < 2; mi++)
        #pragma unroll
        for (int ni = 0; ni < 4; ni++)
            acc[mi][ni] = (f32x4){0.f, 0.f, 0.f, 0.f};

    #pragma unroll
    for (int ks = 0; ks < 4; ks++) {
        int k0 = ks * 32 + quad * 8;
        bf16x8 a1[2], a2[2], a3[2];
        #pragma unroll
        for (int mi = 0; mi < 2; mi++) {
            int row = mi * 16 + lq;         // A: m = lane&15
            float4 f0 = *((const float4*)&xs[row][k0]);
            float4 f1 = *((const float4*)&xs[row][k0 + 4]);
            float fv[8] = {f0.x, f0.y, f0.z, f0.w, f1.x, f1.y, f1.z, f1.w};
            #pragma unroll
            for (int e = 0; e < 8; e++) {
                ushort sa, sb, sc;
                split3(fv[e], sa, sb, sc);
                a1[mi][e] = (short)sa; a2[mi][e] = (short)sb; a3[mi][e] = (short)sc;
            }
        }
        #pragma unroll
        for (int ni = 0; ni < 4; ni++) {
            size_t wo = (size_t)(n0w + ni * 16 + lq) * F + k0;   // B: n = lane&15, k contig
            bf16x8 q1 = *((const bf16x8*)(w1a + wo));
            bf16x8 q2 = *((const bf16x8*)(w1b + wo));
            bf16x8 q3 = *((const bf16x8*)(w1c + wo));
            #pragma unroll
            for (int mi = 0; mi < 2; mi++) {
                acc[mi][ni] = __builtin_amdgcn_mfma_f32_16x16x32_bf16(a1[mi], q1, acc[mi][ni], 0, 0, 0);
                acc[mi][ni] = __builtin_amdgcn_mfma_f32_16x16x32_bf16(a1[mi], q2, acc[mi][ni], 0, 0, 0);
                acc[mi][ni] = __builtin_amdgcn_mfma_f32_16x16x32_bf16(a2[mi], q1, acc[mi][ni], 0, 0, 0);
                acc[mi][ni] = __builtin_amdgcn_mfma_f32_16x16x32_bf16(a1[mi], q3, acc[mi][ni], 0, 0, 0);
                acc[mi][ni] = __builtin_amdgcn_mfma_f32_16x16x32_bf16(a2[mi], q2, acc[mi][ni], 0, 0, 0);
                acc[mi][ni] = __builtin_amdgcn_mfma_f32_16x16x32_bf16(a3[mi], q1, acc[mi][ni], 0, 0, 0);
            }
        }
    }

    // BN + ReLU, D layout col=lane&15 row=quad*4+r -> h1s
    #pragma unroll
    for (int ni = 0; ni < 4; ni++) {
        int h = n0w + ni * 16 + lq;
        float a = ascS[h], d = dscS[h];
        #pragma unroll
        for (int mi = 0; mi < 2; mi++) {
            #pragma unroll
            for (int r = 0; r < 4; r++) {
                int node = mi * 16 + quad * 4 + r;
                float v = acc[mi][ni][r] * a + d;
                h1s[node][h] = v > 0.f ? v : 0.f;
            }
        }
    }
    __syncthreads();   // h1s ready

    // ---- stage 2: h1 @ W2 via MFMA, 6-term split, K=256 split across 4 waves ----
    f32x4 acc2[2][3];
    #pragma unroll
    for (int mi = 0; mi < 2; mi++)
        #pragma unroll
        for (int ni = 0; ni < 3; ni++)
            acc2[mi][ni] = (f32x4){0.f, 0.f, 0.f, 0.f};

    int kb0 = wv * 64;                      // this wave's K-chunk
    #pragma unroll
    for (int ks2 = 0; ks2 < 2; ks2++) {
        int k0 = kb0 + ks2 * 32 + quad * 8;
        bf16x8 a1[2], a2[2], a3[2];
        #pragma unroll
        for (int mi = 0; mi < 2; mi++) {
            int row = mi * 16 + lq;         // A: m = node = lane&15
            float4 f0 = *((const float4*)&h1s[row][k0]);
            float4 f1 = *((const float4*)&h1s[row][k0 + 4]);
            float fv[8] = {f0.x, f0.y, f0.z, f0.w, f1.x, f1.y, f1.z, f1.w};
            #pragma unroll
            for (int e = 0; e < 8; e++) {
                ushort sa, sb, sc;
                split3(fv[e], sa, sb, sc);
                a1[mi][e] = (short)sa; a2[mi][e] = (short)sb; a3[mi][e] = (short)sc;
            }
        }
        #pragma unroll
        for (int ni = 0; ni < 3; ni++) {
            size_t wo = (size_t)(ni * 16 + lq) * H + k0;   // B: n = c = lane&15, k contig
            bf16x8 q1 = *((const bf16x8*)(w2a + wo));
            bf16x8 q2 = *((const bf16x8*)(w2b + wo));
            bf16x8 q3 = *((const bf16x8*)(w2c + wo));
            #pragma unroll
            for (int mi = 0; mi < 2; mi++) {
                acc2[mi][ni] = __builtin_amdgcn_mfma_f32_16x16x32_bf16(a1[mi], q1, acc2[mi][ni], 0, 0, 0);
                acc2[mi][ni] = __builtin_amdgcn_mfma_f32_16x16x32_bf16(a1[mi], q2, acc2[mi][ni], 0, 0, 0);
                acc2[mi][ni] = __builtin_amdgcn_mfma_f32_16x16x32_bf16(a2[mi], q1, acc2[mi][ni], 0, 0, 0);
                acc2[mi][ni] = __builtin_amdgcn_mfma_f32_16x16x32_bf16(a1[mi], q3, acc2[mi][ni], 0, 0, 0);
                acc2[mi][ni] = __builtin_amdgcn_mfma_f32_16x16x32_bf16(a2[mi], q2, acc2[mi][ni], 0, 0, 0);
                acc2[mi][ni] = __builtin_amdgcn_mfma_f32_16x16x32_bf16(a3[mi], q1, acc2[mi][ni], 0, 0, 0);
            }
        }
    }
    __syncthreads();   // all h1s reads done -> h1s region reusable

    // write per-wave partials into h1s overlay: pbB[wv][node][c], stride CP=48
    float* pbB = &h1s[0][0];                // 4*32*48 = 6144 floats (<= 8320)
    #pragma unroll
    for (int mi = 0; mi < 2; mi++)
        #pragma unroll
        for (int ni = 0; ni < 3; ni++)
            #pragma unroll
            for (int r = 0; r < 4; r++) {
                int node = mi * 16 + quad * 4 + r;
                int c = ni * 16 + lq;
                pbB[wv * (TM * CP) + node * CP + c] = acc2[mi][ni][r];
            }
    __syncthreads();

    // reduce 4 wave partials + bias; stash h row; proj partial -> sigmoid
    float* hrow = &h1s[0][0] + 4 * TM * CP; // 32*40 = 1280 floats (6144..7424 <= 8320)
    {
        int ng = t >> 3, cg = t & 7;        // 32 nodes x 8 class-groups
        float p = 0.f;
        #pragma unroll
        for (int j = 0; j < 5; j++) {
            int c = cg * 5 + j;
            float h = pbB[0 * (TM * CP) + ng * CP + c]
                    + pbB[1 * (TM * CP) + ng * CP + c]
                    + pbB[2 * (TM * CP) + ng * CP + c]
                    + pbB[3 * (TM * CP) + ng * CP + c] + b2[c];
            hrow[ng * C + c] = h;
            p += h * pw[c];
        }
        #pragma unroll
        for (int m = 1; m < 8; m <<= 1) p += __shfl_xor(p, m);
        if (cg == 0) sigv[ng] = 1.f / (1.f + expf(-(p + pb[0])));
    }
    __syncthreads();

    // epilogue: write h row (padded stride 48) + out init (dense stride 40)
    if (t < 160) {
        int row = t / 5, p = t % 5;
        int n = n0 + row;
        if (n < N) {
            float4 a = *((const float4*)&hrow[row * C + 8 * p]);
            float4 b = *((const float4*)&hrow[row * C + 8 * p + 4]);
            float4* hp = (float4*)(hbuf + (size_t)n * (RS * 4) + 8 * p);
            hp[0] = a; hp[1] = b;
            float sg = sigv[row];
            float4 oa, ob;
            oa.x = sg * a.x; oa.y = sg * a.y; oa.z = sg * a.z; oa.w = sg * a.w;
            ob.x = sg * b.x; ob.y = sg * b.y; ob.z = sg * b.z; ob.w = sg * b.w;
            float4* op = (float4*)(oacc + (size_t)n * C + 8 * p);
            op[0] = oa; op[1] = ob;
        }
    }
}

// ---------------- one propagation hop, fused with retain-combine ----------------
// 320 threads: 64 nodes/block, 5 lanes/node, 2 float4 per lane.
// Hop-state rows padded to 192B/64B-aligned (RS=12 float4): a full-row gather
// touches exactly 3 cache lines (vs avg 3.5 unpadded). out stays dense [N,40].
// last==1: skip dead nxt write, fuse log_softmax on the final out row.
__global__ void k_hop(const float4* __restrict__ cur4, float4* __restrict__ nxt4,
                      float4* __restrict__ oacc4, const int* __restrict__ rp,
                      const int2* __restrict__ ep,
                      const float* __restrict__ pw, const float* __restrict__ pb,
                      int N, int last) {
    __shared__ float red[320];
    __shared__ float sig[64];
    __shared__ float statm[64];
    __shared__ float stats[64];
    int t = threadIdx.x;
    int nl = t / 5, p = t % 5;
    int n = blockIdx.x * 64 + nl;
    int c0 = 2 * p;
    float4 a0 = make_float4(0.f, 0.f, 0.f, 0.f);
    float4 a1 = make_float4(0.f, 0.f, 0.f, 0.f);
    size_t o = (size_t)n * 10 + c0;       // dense (oacc/out)
    size_t q = (size_t)n * RS + c0;       // padded (hop buffers)
    if (n < N) {
        int b = rp[n], e = rp[n + 1];
        int j = b;
        for (; j + 4 <= e; j += 4) {
            int2 e0 = ep[j], e1 = ep[j + 1], e2 = ep[j + 2], e3 = ep[j + 3];
            const float4* r0 = cur4 + (size_t)e0.x * RS + c0;
            const float4* r1 = cur4 + (size_t)e1.x * RS + c0;
            const float4* r2 = cur4 + (size_t)e2.x * RS + c0;
            const float4* r3 = cur4 + (size_t)e3.x * RS + c0;
            float4 v00 = r0[0], v01 = r0[1];
            float4 v10 = r1[0], v11 = r1[1];
            float4 v20 = r2[0], v21 = r2[1];
            float4 v30 = r3[0], v31 = r3[1];
            float w0 = __int_as_float(e0.y), w1 = __int_as_float(e1.y);
            float w2 = __int_as_float(e2.y), w3 = __int_as_float(e3.y);
            a0.x += w0 * v00.x; a0.y += w0 * v00.y; a0.z += w0 * v00.z; a0.w += w0 * v00.w;
            a1.x += w0 * v01.x; a1.y += w0 * v01.y; a1.z += w0 * v01.z; a1.w += w0 * v01.w;
            a0.x += w1 * v10.x; a0.y += w1 * v10.y; a0.z += w1 * v10.z; a0.w += w1 * v10.w;
            a1.x += w1 * v11.x; a1.y += w1 * v11.y; a1.z += w1 * v11.z; a1.w += w1 * v11.w;
            a0.x += w2 * v20.x; a0.y += w2 * v20.y; a0.z += w2 * v20.z; a0.w += w2 * v20.w;
            a1.x += w2 * v21.x; a1.y += w2 * v21.y; a1.z += w2 * v21.z; a1.w += w2 * v21.w;
            a0.x += w3 * v30.x; a0.y += w3 * v30.y; a0.z += w3 * v30.z; a0.w += w3 * v30.w;
            a1.x += w3 * v31.x; a1.y += w3 * v31.y; a1.z += w3 * v31.z; a1.w += w3 * v31.w;
        }
        if (j + 2 <= e) {
            int2 e0 = ep[j], e1 = ep[j + 1];
            const float4* r0 = cur4 + (size_t)e0.x * RS + c0;
            const float4* r1 = cur4 + (size_t)e1.x * RS + c0;
            float4 v00 = r0[0], v01 = r0[1];
            float4 v10 = r1[0], v11 = r1[1];
            float w0 = __int_as_float(e0.y), w1 = __int_as_float(e1.y);
            a0.x += w0 * v00.x; a0.y += w0 * v00.y; a0.z += w0 * v00.z; a0.w += w0 * v00.w;
            a1.x += w0 * v01.x; a1.y += w0 * v01.y; a1.z += w0 * v01.z; a1.w += w0 * v01.w;
            a0.x += w1 * v10.x; a0.y += w1 * v10.y; a0.z += w1 * v10.z; a0.w += w1 * v10.w;
            a1.x += w1 * v11.x; a1.y += w1 * v11.y; a1.z += w1 * v11.z; a1.w += w1 * v11.w;
            j += 2;
        }
        if (j < e) {
            int2 e0 = ep[j];
            const float4* r0 = cur4 + (size_t)e0.x * RS + c0;
            float4 v00 = r0[0], v01 = r0[1];
            float w0 = __int_as_float(e0.y);
            a0.x += w0 * v00.x; a0.y += w0 * v00.y; a0.z += w0 * v00.z; a0.w += w0 * v00.w;
            a1.x += w0 * v01.x; a1.y += w0 * v01.y; a1.z += w0 * v01.z; a1.w += w0 * v01.w;
        }
        if (!last) {
            nxt4[q] = a0;
            nxt4[q + 1] = a1;
        }
    }
    // retain-combine
    float4 pw0 = ((const float4*)pw)[c0];
    float4 pw1 = ((const float4*)pw)[c0 + 1];
    red[t] = a0.x * pw0.x + a0.y * pw0.y + a0.z * pw0.z + a0.w * pw0.w
           + a1.x * pw1.x + a1.y * pw1.y + a1.z * pw1.z + a1.w * pw1.w;
    __syncthreads();
    if (p == 0) {
        float s = red[t] + red[t + 1] + red[t + 2] + red[t + 3] + red[t + 4];
        sig[nl] = 1.f / (1.f + expf(-(s + pb[0])));
    }
    __syncthreads();
    float4 v0 = make_float4(0.f, 0.f, 0.f, 0.f);
    float4 v1 = make_float4(0.f, 0.f, 0.f, 0.f);
    if (n < N) {
        float sg = sig[nl];
        v0 = oacc4[o]; v1 = oacc4[o + 1];
        v0.x += sg * a0.x; v0.y += sg * a0.y; v0.z += sg * a0.z; v0.w += sg * a0.w;
        v1.x += sg * a1.x; v1.y += sg * a1.y; v1.z += sg * a1.z; v1.w += sg * a1.w;
        if (!last) {
            oacc4[o] = v0;
            oacc4[o + 1] = v1;
        }
    }
    if (last) {
        // fused log_softmax over the 40 classes (spread across 5 lanes per node)
        bool ok = n < N;
        float mx = fmaxf(fmaxf(fmaxf(v0.x, v0.y), fmaxf(v0.z, v0.w)),
                         fmaxf(fmaxf(v1.x, v1.y), fmaxf(v1.z, v1.w)));
        red[t] = ok ? mx : -1e30f;
        __syncthreads();
        if (p == 0) {
            float m = fmaxf(fmaxf(fmaxf(red[t], red[t + 1]), fmaxf(red[t + 2], red[t + 3])),
                            red[t + 4]);
            statm[nl] = m;
        }
        __syncthreads();
        float m = statm[nl];
        float s = 0.f;
        if (ok) {
            s = expf(v0.x - m) + expf(v0.y - m) + expf(v0.z - m) + expf(v0.w - m)
              + expf(v1.x - m) + expf(v1.y - m) + expf(v1.z - m) + expf(v1.w - m);
        }
        red[t] = s;
        __syncthreads();
        if (p == 0) {
            float ssum = red[t] + red[t + 1] + red[t + 2] + red[t + 3] + red[t + 4];
            stats[nl] = logf(ssum);
        }
        __syncthreads();
        if (ok) {
            float ls = statm[nl] + stats[nl];
            oacc4[o]     = make_float4(v0.x - ls, v0.y - ls, v0.z - ls, v0.w - ls);
            oacc4[o + 1] = make_float4(v1.x - ls, v1.y - ls, v1.z - ls, v1.w - ls);
        }
    }
}

extern "C" void kernel_launch(void* const* d_in, const int* in_sizes, int n_in,
                              void* d_out, int out_size, void* d_ws, size_t ws_size,
                              hipStream_t stream) {
    const float* x   = (const float*)d_in[0];
    const int*   ei  = (const int*)d_in[1];     // [2,E]: src row then dst row
    const float* nrm = (const float*)d_in[2];
    const float* W1  = (const float*)d_in[3];
    const float* b1  = (const float*)d_in[4];
    const float* g   = (const float*)d_in[5];
    const float* be  = (const float*)d_in[6];
    const float* mu  = (const float*)d_in[7];
    const float* var = (const float*)d_in[8];
    const float* W2  = (const float*)d_in[9];
    const float* b2  = (const float*)d_in[10];
    const float* pw  = (const float*)d_in[11];
    const float* pb  = (const float*)d_in[12];
    float* out = (float*)d_out;

    int N = in_sizes[0] / F;
    int E = in_sizes[2];

    char* w = (char*)d_ws;
    auto alloc = [&](size_t bytes) {
        void* p = (void*)w;
        w += ((bytes + 255) / 256) * 256;
        return p;
    };
    int*    rp     = (int*)alloc((size_t)(N + 1) * 4);
    int*    cursor = (int*)alloc((size_t)(N + 1) * 4);
    int*    bsum   = (int*)alloc(1024);
    int2*   ep     = (int2*)alloc((size_t)E * 8);
    ushort* w1a    = (ushort*)alloc((size_t)F * H * 2);
    ushort* w1b    = (ushort*)alloc((size_t)F * H * 2);
    ushort* w1c    = (ushort*)alloc((size_t)F * H * 2);
    ushort* w2a    = (ushort*)alloc((size_t)CP * H * 2);
    ushort* w2b    = (ushort*)alloc((size_t)CP * H * 2);
    ushort* w2c    = (ushort*)alloc((size_t)CP * H * 2);
    float*  bufA   = (float*)alloc((size_t)N * (RS * 4) * 4);
    float*  bufB   = (float*)alloc((size_t)N * (RS * 4) * 4);

    hipMemsetAsync(cursor, 0, (size_t)(N + 1) * 4, stream);

    k_count<<<(E + 255) / 256, 256, 0, stream>>>(ei + E, E, cursor);

    int n1 = N + 1;
    int NB = (n1 + 4095) / 4096;
    k_scan1<<<NB, 256, 0, stream>>>(cursor, n1, bsum);
    k_scan2<<<1, 64, 0, stream>>>(bsum, NB);
    k_scan3<<<NB, 256, 0, stream>>>(cursor, n1, bsum, rp);

    hipMemsetAsync(cursor, 0, (size_t)(N + 1) * 4, stream);
    k_fill<<<(E + 255) / 256, 256, 0, stream>>>(ei, ei + E, nrm, E, rp, cursor, ep);

    k_wsplit<<<(F * H + 255) / 256, 256, 0, stream>>>(W1, w1a, w1b, w1c);
    k_w2split<<<(CP * H + 255) / 256, 256, 0, stream>>>(W2, w2a, w2b, w2c);

    k_mlp<<<(N + TM - 1) / TM, 256, 0, stream>>>(x, w1a, w1b, w1c, w2a, w2b, w2c,
                                                 b1, g, be, mu, var,
                                                 b2, pw, pb, bufA, out, N);

    int nodeBlocks64 = (N + 63) / 64;
    float* cur = bufA;
    float* nxt = bufB;
    for (int k = 0; k < KHOPS; k++) {
        k_hop<<<nodeBlocks64, 320, 0, stream>>>((const float4*)cur, (float4*)nxt, (float4*)out,
                                                rp, ep, pw, pb, N, (k == KHOPS - 1) ? 1 : 0);
        float* tmp = cur; cur = nxt; nxt = tmp;
    }
}

// Round 6
// 959.308 us; speedup vs baseline: 1.1217x; 1.0608x over previous
//
#include <hip/hip_runtime.h>
#include <hip/hip_bf16.h>
#include <math.h>

#define F 128
#define H 256
#define C 40
#define CP 48          // padded class dim for MFMA stage 2
#define KHOPS 10
#define TM 32

typedef short bf16x8 __attribute__((ext_vector_type(8)));
typedef float f32x4 __attribute__((ext_vector_type(4)));

// round-to-nearest bf16
__device__ __forceinline__ ushort bf16rn(float v) {
    unsigned u = __float_as_uint(v);
    unsigned r = (u + 0x7FFFu + ((u >> 16) & 1u)) >> 16;
    return (ushort)r;
}

// 2-way bf16 split (RN): v = f1 + f2 + O(2^-18 v); subtraction exact (Sterbenz)
__device__ __forceinline__ void split2(float v, ushort& s1, ushort& s2) {
    ushort h = bf16rn(v);
    s1 = h;
    float f1 = __uint_as_float(((unsigned)h) << 16);
    float r = v - f1;
    s2 = bf16rn(r);
}

// ---------------- CSR build ----------------
__global__ void k_count(const int* __restrict__ dst, int E, int* __restrict__ cnt) {
    int e = blockIdx.x * 256 + threadIdx.x;
    if (e < E) atomicAdd(&cnt[dst[e]], 1);
}

__global__ void k_scan1(const int* __restrict__ cnt, int n, int* __restrict__ bsum) {
    __shared__ int sh[256];
    int t = threadIdx.x;
    int base = blockIdx.x * 4096 + t * 16;
    int s = 0;
    for (int i = 0; i < 16; i++) { int idx = base + i; if (idx < n) s += cnt[idx]; }
    sh[t] = s; __syncthreads();
    for (int o = 128; o > 0; o >>= 1) {
        if (t < o) sh[t] += sh[t + o];
        __syncthreads();
    }
    if (t == 0) bsum[blockIdx.x] = sh[0];
}

__global__ void k_scan2(int* __restrict__ bsum, int nb) {
    if (threadIdx.x == 0) {
        int acc = 0;
        for (int i = 0; i < nb; i++) { int v = bsum[i]; bsum[i] = acc; acc += v; }
    }
}

__global__ void k_scan3(const int* __restrict__ cnt, int n, const int* __restrict__ bsum,
                        int* __restrict__ rp) {
    __shared__ int sh[256];
    int t = threadIdx.x;
    int base = blockIdx.x * 4096 + t * 16;
    int local[16]; int s = 0;
    for (int i = 0; i < 16; i++) {
        int idx = base + i;
        int v = (idx < n) ? cnt[idx] : 0;
        local[i] = v; s += v;
    }
    sh[t] = s; __syncthreads();
    for (int o = 1; o < 256; o <<= 1) {
        int v = (t >= o) ? sh[t - o] : 0;
        __syncthreads();
        sh[t] += v;
        __syncthreads();
    }
    int excl = (t == 0) ? 0 : sh[t - 1];
    int run = bsum[blockIdx.x] + excl;
    for (int i = 0; i < 16; i++) {
        int idx = base + i;
        if (idx < n) { rp[idx] = run; run += local[i]; }
    }
}

__global__ void k_fill(const int* __restrict__ src, const int* __restrict__ dst,
                       const float* __restrict__ nrm, int E, const int* __restrict__ rp,
                       int* __restrict__ cur, int2* __restrict__ ep) {
    int e = blockIdx.x * 256 + threadIdx.x;
    if (e < E) {
        int d = dst[e];
        int p = rp[d] + atomicAdd(&cur[d], 1);
        ep[p] = make_int2(src[e], __float_as_int(nrm[e]));
    }
}

// ---- W1 split to 2 bf16 arrays in B-fragment layout [h][f] (W1^T) ----
__global__ void k_wsplit(const float* __restrict__ W1, ushort* __restrict__ w1a,
                         ushort* __restrict__ w1b) {
    int t = blockIdx.x * 256 + threadIdx.x;
    if (t < F * H) {
        int h = t / F, f = t % F;
        ushort a, b;
        split2(W1[(size_t)f * H + h], a, b);
        w1a[t] = a; w1b[t] = b;
    }
}

// ---- W2 split to 2 bf16 arrays in B-fragment layout [c][h], c padded to 48 ----
__global__ void k_w2split(const float* __restrict__ W2, ushort* __restrict__ w2a,
                          ushort* __restrict__ w2b) {
    int t = blockIdx.x * 256 + threadIdx.x;
    if (t < CP * H) {
        int c = t / H, k = t % H;
        float v = (c < C) ? W2[(size_t)k * C + c] : 0.f;
        ushort a, b;
        split2(v, a, b);
        w2a[t] = a; w2b[t] = b;
    }
}

// ------- fused MLP: MFMA split2-bf16 Linear(128->256) + BN+ReLU + MFMA split2-bf16
//         Linear(256->40) + snapshot-0 retain-combine -------
// 3-term split product (a1w1 + a1w2 + a2w1); dropped a2w2 ~ 2^-18 relative.
// LDS: xs 16896 + h1s 33280 + asc/dsc 2048 + sigv 128 ~= 52.4 KB -> 3 blocks/CU.
__launch_bounds__(256, 3)
__global__ void k_mlp(const float* __restrict__ x,
                      const ushort* __restrict__ w1a, const ushort* __restrict__ w1b,
                      const ushort* __restrict__ w2a, const ushort* __restrict__ w2b,
                      const float* __restrict__ b1, const float* __restrict__ g,
                      const float* __restrict__ be, const float* __restrict__ mu,
                      const float* __restrict__ var,
                      const float* __restrict__ b2, const float* __restrict__ pw,
                      const float* __restrict__ pb,
                      float* __restrict__ hbuf, float* __restrict__ oacc, int N) {
    __shared__ float xs[TM][132];     // fp32 x tile (stage 1 A operand)
    __shared__ float h1s[TM][260];    // fp32 h1; also overlaid: stage-2 partials + hrow
    __shared__ float ascS[H], dscS[H];
    __shared__ float sigv[TM];

    int t = threadIdx.x;
    int n0 = blockIdx.x * TM;

    // stage x tile (fp32)
    for (int kk = 0; kk < 4; kk++) {
        int idx = kk * 256 + t;             // 1024 float4 = 32 nodes x 32 f4
        int node = idx >> 5, f4 = idx & 31;
        int n = n0 + node;
        float4 v = (n < N) ? ((const float4*)x)[(size_t)n * (F / 4) + f4]
                           : make_float4(0.f, 0.f, 0.f, 0.f);
        *((float4*)&xs[node][f4 * 4]) = v;
    }
    // BN coefficients (t == h, exactly 256 threads)
    {
        float a = g[t] * rsqrtf(var[t] + 1e-5f);
        ascS[t] = a;
        dscS[t] = (b1[t] - mu[t]) * a + be[t];
    }
    __syncthreads();

    // ---- stage 1: x @ W1 via MFMA, 3-term split product; split2 done in-register ----
    int lane = t & 63, wv = t >> 6, quad = lane >> 4, lq = lane & 15;
    int n0w = wv * 64;                      // this wave's H-chunk
    f32x4 acc[2][4];
    #pragma unroll
    for (int mi = 0; mi < 2; mi++)
        #pragma unroll
        for (int ni = 0; ni < 4; ni++)
            acc[mi][ni] = (f32x4){0.f, 0.f, 0.f, 0.f};

    #pragma unroll
    for (int ks = 0; ks < 4; ks++) {
        int k0 = ks * 32 + quad * 8;
        bf16x8 a1[2], a2[2];
        #pragma unroll
        for (int mi = 0; mi < 2; mi++) {
            int row = mi * 16 + lq;         // A: m = lane&15
            float4 f0 = *((const float4*)&xs[row][k0]);
            float4 f1 = *((const float4*)&xs[row][k0 + 4]);
            float fv[8] = {f0.x, f0.y, f0.z, f0.w, f1.x, f1.y, f1.z, f1.w};
            #pragma unroll
            for (int e = 0; e < 8; e++) {
                ushort sa, sb;
                split2(fv[e], sa, sb);
                a1[mi][e] = (short)sa; a2[mi][e] = (short)sb;
            }
        }
        #pragma unroll
        for (int ni = 0; ni < 4; ni++) {
            size_t wo = (size_t)(n0w + ni * 16 + lq) * F + k0;   // B: n = lane&15, k contig
            bf16x8 q1 = *((const bf16x8*)(w1a + wo));
            bf16x8 q2 = *((const bf16x8*)(w1b + wo));
            #pragma unroll
            for (int mi = 0; mi < 2; mi++) {
                acc[mi][ni] = __builtin_amdgcn_mfma_f32_16x16x32_bf16(a1[mi], q1, acc[mi][ni], 0, 0, 0);
                acc[mi][ni] = __builtin_amdgcn_mfma_f32_16x16x32_bf16(a1[mi], q2, acc[mi][ni], 0, 0, 0);
                acc[mi][ni] = __builtin_amdgcn_mfma_f32_16x16x32_bf16(a2[mi], q1, acc[mi][ni], 0, 0, 0);
            }
        }
    }

    // BN + ReLU, D layout col=lane&15 row=quad*4+r -> h1s
    #pragma unroll
    for (int ni = 0; ni < 4; ni++) {
        int h = n0w + ni * 16 + lq;
        float a = ascS[h], d = dscS[h];
        #pragma unroll
        for (int mi = 0; mi < 2; mi++) {
            #pragma unroll
            for (int r = 0; r < 4; r++) {
                int node = mi * 16 + quad * 4 + r;
                float v = acc[mi][ni][r] * a + d;
                h1s[node][h] = v > 0.f ? v : 0.f;
            }
        }
    }
    __syncthreads();   // h1s ready

    // ---- stage 2: h1 @ W2 via MFMA, 3-term split, K=256 split across 4 waves ----
    f32x4 acc2[2][3];
    #pragma unroll
    for (int mi = 0; mi < 2; mi++)
        #pragma unroll
        for (int ni = 0; ni < 3; ni++)
            acc2[mi][ni] = (f32x4){0.f, 0.f, 0.f, 0.f};

    int kb0 = wv * 64;                      // this wave's K-chunk
    #pragma unroll
    for (int ks2 = 0; ks2 < 2; ks2++) {
        int k0 = kb0 + ks2 * 32 + quad * 8;
        bf16x8 a1[2], a2[2];
        #pragma unroll
        for (int mi = 0; mi < 2; mi++) {
            int row = mi * 16 + lq;         // A: m = node = lane&15
            float4 f0 = *((const float4*)&h1s[row][k0]);
            float4 f1 = *((const float4*)&h1s[row][k0 + 4]);
            float fv[8] = {f0.x, f0.y, f0.z, f0.w, f1.x, f1.y, f1.z, f1.w};
            #pragma unroll
            for (int e = 0; e < 8; e++) {
                ushort sa, sb;
                split2(fv[e], sa, sb);
                a1[mi][e] = (short)sa; a2[mi][e] = (short)sb;
            }
        }
        #pragma unroll
        for (int ni = 0; ni < 3; ni++) {
            size_t wo = (size_t)(ni * 16 + lq) * H + k0;   // B: n = c = lane&15, k contig
            bf16x8 q1 = *((const bf16x8*)(w2a + wo));
            bf16x8 q2 = *((const bf16x8*)(w2b + wo));
            #pragma unroll
            for (int mi = 0; mi < 2; mi++) {
                acc2[mi][ni] = __builtin_amdgcn_mfma_f32_16x16x32_bf16(a1[mi], q1, acc2[mi][ni], 0, 0, 0);
                acc2[mi][ni] = __builtin_amdgcn_mfma_f32_16x16x32_bf16(a1[mi], q2, acc2[mi][ni], 0, 0, 0);
                acc2[mi][ni] = __builtin_amdgcn_mfma_f32_16x16x32_bf16(a2[mi], q1, acc2[mi][ni], 0, 0, 0);
            }
        }
    }
    __syncthreads();   // all h1s reads done -> h1s region reusable

    // write per-wave partials into h1s overlay: pbB[wv][node][c], stride CP=48
    float* pbB = &h1s[0][0];                // 4*32*48 = 6144 floats (<= 8320)
    #pragma unroll
    for (int mi = 0; mi < 2; mi++)
        #pragma unroll
        for (int ni = 0; ni < 3; ni++)
            #pragma unroll
            for (int r = 0; r < 4; r++) {
                int node = mi * 16 + quad * 4 + r;
                int c = ni * 16 + lq;
                pbB[wv * (TM * CP) + node * CP + c] = acc2[mi][ni][r];
            }
    __syncthreads();

    // reduce 4 wave partials + bias; stash h row; proj partial -> sigmoid
    float* hrow = &h1s[0][0] + 4 * TM * CP; // 32*40 = 1280 floats (6144..7424 <= 8320)
    {
        int ng = t >> 3, cg = t & 7;        // 32 nodes x 8 class-groups
        float p = 0.f;
        #pragma unroll
        for (int j = 0; j < 5; j++) {
            int c = cg * 5 + j;
            float h = pbB[0 * (TM * CP) + ng * CP + c]
                    + pbB[1 * (TM * CP) + ng * CP + c]
                    + pbB[2 * (TM * CP) + ng * CP + c]
                    + pbB[3 * (TM * CP) + ng * CP + c] + b2[c];
            hrow[ng * C + c] = h;
            p += h * pw[c];
        }
        #pragma unroll
        for (int m = 1; m < 8; m <<= 1) p += __shfl_xor(p, m);
        if (cg == 0) sigv[ng] = 1.f / (1.f + expf(-(p + pb[0])));
    }
    __syncthreads();

    // epilogue: write h row + out init (32 rows x 5 packs of 8 floats)
    if (t < 160) {
        int row = t / 5, p = t % 5;
        int n = n0 + row;
        if (n < N) {
            float4 a = *((const float4*)&hrow[row * C + 8 * p]);
            float4 b = *((const float4*)&hrow[row * C + 8 * p + 4]);
            float4* hp = (float4*)(hbuf + (size_t)n * C + 8 * p);
            hp[0] = a; hp[1] = b;
            float sg = sigv[row];
            float4 oa, ob;
            oa.x = sg * a.x; oa.y = sg * a.y; oa.z = sg * a.z; oa.w = sg * a.w;
            ob.x = sg * b.x; ob.y = sg * b.y; ob.z = sg * b.z; ob.w = sg * b.w;
            float4* op = (float4*)(oacc + (size_t)n * C + 8 * p);
            op[0] = oa; op[1] = ob;
        }
    }
}

// ---------------- one propagation hop, fused with retain-combine ----------------
// 320 threads: 64 nodes/block, 5 lanes/node, 2 float4 per lane. (round-2 proven form)
// last==1: skip dead nxt write, fuse log_softmax on the final out row.
__global__ void k_hop(const float4* __restrict__ cur4, float4* __restrict__ nxt4,
                      float4* __restrict__ oacc4, const int* __restrict__ rp,
                      const int2* __restrict__ ep,
                      const float* __restrict__ pw, const float* __restrict__ pb,
                      int N, int last) {
    __shared__ float red[320];
    __shared__ float sig[64];
    __shared__ float statm[64];
    __shared__ float stats[64];
    int t = threadIdx.x;
    int nl = t / 5, p = t % 5;
    int n = blockIdx.x * 64 + nl;
    int c0 = 2 * p;
    float4 a0 = make_float4(0.f, 0.f, 0.f, 0.f);
    float4 a1 = make_float4(0.f, 0.f, 0.f, 0.f);
    size_t o = (size_t)n * 10 + c0;
    if (n < N) {
        int b = rp[n], e = rp[n + 1];
        int j = b;
        for (; j + 4 <= e; j += 4) {
            int2 e0 = ep[j], e1 = ep[j + 1], e2 = ep[j + 2], e3 = ep[j + 3];
            const float4* r0 = cur4 + (size_t)e0.x * 10 + c0;
            const float4* r1 = cur4 + (size_t)e1.x * 10 + c0;
            const float4* r2 = cur4 + (size_t)e2.x * 10 + c0;
            const float4* r3 = cur4 + (size_t)e3.x * 10 + c0;
            float4 v00 = r0[0], v01 = r0[1];
            float4 v10 = r1[0], v11 = r1[1];
            float4 v20 = r2[0], v21 = r2[1];
            float4 v30 = r3[0], v31 = r3[1];
            float w0 = __int_as_float(e0.y), w1 = __int_as_float(e1.y);
            float w2 = __int_as_float(e2.y), w3 = __int_as_float(e3.y);
            a0.x += w0 * v00.x; a0.y += w0 * v00.y; a0.z += w0 * v00.z; a0.w += w0 * v00.w;
            a1.x += w0 * v01.x; a1.y += w0 * v01.y; a1.z += w0 * v01.z; a1.w += w0 * v01.w;
            a0.x += w1 * v10.x; a0.y += w1 * v10.y; a0.z += w1 * v10.z; a0.w += w1 * v10.w;
            a1.x += w1 * v11.x; a1.y += w1 * v11.y; a1.z += w1 * v11.z; a1.w += w1 * v11.w;
            a0.x += w2 * v20.x; a0.y += w2 * v20.y; a0.z += w2 * v20.z; a0.w += w2 * v20.w;
            a1.x += w2 * v21.x; a1.y += w2 * v21.y; a1.z += w2 * v21.z; a1.w += w2 * v21.w;
            a0.x += w3 * v30.x; a0.y += w3 * v30.y; a0.z += w3 * v30.z; a0.w += w3 * v30.w;
            a1.x += w3 * v31.x; a1.y += w3 * v31.y; a1.z += w3 * v31.z; a1.w += w3 * v31.w;
        }
        if (j + 2 <= e) {
            int2 e0 = ep[j], e1 = ep[j + 1];
            const float4* r0 = cur4 + (size_t)e0.x * 10 + c0;
            const float4* r1 = cur4 + (size_t)e1.x * 10 + c0;
            float4 v00 = r0[0], v01 = r0[1];
            float4 v10 = r1[0], v11 = r1[1];
            float w0 = __int_as_float(e0.y), w1 = __int_as_float(e1.y);
            a0.x += w0 * v00.x; a0.y += w0 * v00.y; a0.z += w0 * v00.z; a0.w += w0 * v00.w;
            a1.x += w0 * v01.x; a1.y += w0 * v01.y; a1.z += w0 * v01.z; a1.w += w0 * v01.w;
            a0.x += w1 * v10.x; a0.y += w1 * v10.y; a0.z += w1 * v10.z; a0.w += w1 * v10.w;
            a1.x += w1 * v11.x; a1.y += w1 * v11.y; a1.z += w1 * v11.z; a1.w += w1 * v11.w;
            j += 2;
        }
        if (j < e) {
            int2 e0 = ep[j];
            const float4* r0 = cur4 + (size_t)e0.x * 10 + c0;
            float4 v00 = r0[0], v01 = r0[1];
            float w0 = __int_as_float(e0.y);
            a0.x += w0 * v00.x; a0.y += w0 * v00.y; a0.z += w0 * v00.z; a0.w += w0 * v00.w;
            a1.x += w0 * v01.x; a1.y += w0 * v01.y; a1.z += w0 * v01.z; a1.w += w0 * v01.w;
        }
        if (!last) {
            nxt4[o] = a0;
            nxt4[o + 1] = a1;
        }
    }
    // retain-combine
    float4 pw0 = ((const float4*)pw)[c0];
    float4 pw1 = ((const float4*)pw)[c0 + 1];
    red[t] = a0.x * pw0.x + a0.y * pw0.y + a0.z * pw0.z + a0.w * pw0.w
           + a1.x * pw1.x + a1.y * pw1.y + a1.z * pw1.z + a1.w * pw1.w;
    __syncthreads();
    if (p == 0) {
        float s = red[t] + red[t + 1] + red[t + 2] + red[t + 3] + red[t + 4];
        sig[nl] = 1.f / (1.f + expf(-(s + pb[0])));
    }
    __syncthreads();
    float4 v0 = make_float4(0.f, 0.f, 0.f, 0.f);
    float4 v1 = make_float4(0.f, 0.f, 0.f, 0.f);
    if (n < N) {
        float sg = sig[nl];
        v0 = oacc4[o]; v1 = oacc4[o + 1];
        v0.x += sg * a0.x; v0.y += sg * a0.y; v0.z += sg * a0.z; v0.w += sg * a0.w;
        v1.x += sg * a1.x; v1.y += sg * a1.y; v1.z += sg * a1.z; v1.w += sg * a1.w;
        if (!last) {
            oacc4[o] = v0;
            oacc4[o + 1] = v1;
        }
    }
    if (last) {
        // fused log_softmax over the 40 classes (spread across 5 lanes per node)
        bool ok = n < N;
        float mx = fmaxf(fmaxf(fmaxf(v0.x, v0.y), fmaxf(v0.z, v0.w)),
                         fmaxf(fmaxf(v1.x, v1.y), fmaxf(v1.z, v1.w)));
        red[t] = ok ? mx : -1e30f;
        __syncthreads();
        if (p == 0) {
            float m = fmaxf(fmaxf(fmaxf(red[t], red[t + 1]), fmaxf(red[t + 2], red[t + 3])),
                            red[t + 4]);
            statm[nl] = m;
        }
        __syncthreads();
        float m = statm[nl];
        float s = 0.f;
        if (ok) {
            s = expf(v0.x - m) + expf(v0.y - m) + expf(v0.z - m) + expf(v0.w - m)
              + expf(v1.x - m) + expf(v1.y - m) + expf(v1.z - m) + expf(v1.w - m);
        }
        red[t] = s;
        __syncthreads();
        if (p == 0) {
            float ssum = red[t] + red[t + 1] + red[t + 2] + red[t + 3] + red[t + 4];
            stats[nl] = logf(ssum);
        }
        __syncthreads();
        if (ok) {
            float ls = statm[nl] + stats[nl];
            oacc4[o]     = make_float4(v0.x - ls, v0.y - ls, v0.z - ls, v0.w - ls);
            oacc4[o + 1] = make_float4(v1.x - ls, v1.y - ls, v1.z - ls, v1.w - ls);
        }
    }
}

extern "C" void kernel_launch(void* const* d_in, const int* in_sizes, int n_in,
                              void* d_out, int out_size, void* d_ws, size_t ws_size,
                              hipStream_t stream) {
    const float* x   = (const float*)d_in[0];
    const int*   ei  = (const int*)d_in[1];     // [2,E]: src row then dst row
    const float* nrm = (const float*)d_in[2];
    const float* W1  = (const float*)d_in[3];
    const float* b1  = (const float*)d_in[4];
    const float* g   = (const float*)d_in[5];
    const float* be  = (const float*)d_in[6];
    const float* mu  = (const float*)d_in[7];
    const float* var = (const float*)d_in[8];
    const float* W2  = (const float*)d_in[9];
    const float* b2  = (const float*)d_in[10];
    const float* pw  = (const float*)d_in[11];
    const float* pb  = (const float*)d_in[12];
    float* out = (float*)d_out;

    int N = in_sizes[0] / F;
    int E = in_sizes[2];

    char* w = (char*)d_ws;
    auto alloc = [&](size_t bytes) {
        void* p = (void*)w;
        w += ((bytes + 255) / 256) * 256;
        return p;
    };
    int*    rp     = (int*)alloc((size_t)(N + 1) * 4);
    int*    cursor = (int*)alloc((size_t)(N + 1) * 4);
    int*    bsum   = (int*)alloc(1024);
    int2*   ep     = (int2*)alloc((size_t)E * 8);
    ushort* w1a    = (ushort*)alloc((size_t)F * H * 2);
    ushort* w1b    = (ushort*)alloc((size_t)F * H * 2);
    ushort* w2a    = (ushort*)alloc((size_t)CP * H * 2);
    ushort* w2b    = (ushort*)alloc((size_t)CP * H * 2);
    float*  bufA   = (float*)alloc((size_t)N * C * 4);
    float*  bufB   = (float*)alloc((size_t)N * C * 4);

    hipMemsetAsync(cursor, 0, (size_t)(N + 1) * 4, stream);

    k_count<<<(E + 255) / 256, 256, 0, stream>>>(ei + E, E, cursor);

    int n1 = N + 1;
    int NB = (n1 + 4095) / 4096;
    k_scan1<<<NB, 256, 0, stream>>>(cursor, n1, bsum);
    k_scan2<<<1, 64, 0, stream>>>(bsum, NB);
    k_scan3<<<NB, 256, 0, stream>>>(cursor, n1, bsum, rp);

    hipMemsetAsync(cursor, 0, (size_t)(N + 1) * 4, stream);
    k_fill<<<(E + 255) / 256, 256, 0, stream>>>(ei, ei + E, nrm, E, rp, cursor, ep);

    k_wsplit<<<(F * H + 255) / 256, 256, 0, stream>>>(W1, w1a, w1b);
    k_w2split<<<(CP * H + 255) / 256, 256, 0, stream>>>(W2, w2a, w2b);

    k_mlp<<<(N + TM - 1) / TM, 256, 0, stream>>>(x, w1a, w1b, w2a, w2b,
                                                 b1, g, be, mu, var,
                                                 b2, pw, pb, bufA, out, N);

    int nodeBlocks64 = (N + 63) / 64;
    float* cur = bufA;
    float* nxt = bufB;
    for (int k = 0; k < KHOPS; k++) {
        k_hop<<<nodeBlocks64, 320, 0, stream>>>((const float4*)cur, (float4*)nxt, (float4*)out,
                                                rp, ep, pw, pb, N, (k == KHOPS - 1) ? 1 : 0);
        float* tmp = cur; cur = nxt; nxt = tmp;
    }
}